// Round 2
// baseline (876.610 us; speedup 1.0000x reference)
//
#include <hip/hip_runtime.h>
#include <cstdint>
#include <cstddef>

typedef unsigned long long u64;

// ---------------- prep 1: weight transposes (pre-converted to f64) + folded output weights ----------------
__global__ void prep_weights(const float* __restrict__ W1, const float* __restrict__ W2,
                             const float* __restrict__ W3, const float* __restrict__ Wc2,
                             const float* __restrict__ bc2, const float* __restrict__ WA,
                             double* __restrict__ Wt1, double* __restrict__ Wt2,
                             double* __restrict__ Wt3, double* __restrict__ wEff,
                             double* __restrict__ bEff)
{
  int id = blockIdx.x * 256 + (int)threadIdx.x;
  if (id < 65536){ int i = id >> 8, j = id & 255; Wt2[(i<<8)+j] = (double)W2[j*256+i]; }   // W2 (256,256) -> Wt2[i][j]
  if (id < 3072){ int k = id >> 8, j = id & 255; Wt1[(k<<8)+j] = (double)W1[j*12+k]; }     // W1 (256,12) -> Wt1[k][j]
  if (id < 1024){ int i = id >> 2, jj = id & 3; Wt3[id] = (jj<3) ? (double)W3[jj*256+i] : 0.0; } // W3 -> Wt3[i][0..2], pad col3=0
  if (id < 32){ double s = 0.0; for (int c=0;c<64;c++) s += (double)WA[c]*(double)Wc2[c*32+id]; wEff[id] = s; }
  if (id == 32){ double s = 0.0; for (int c=0;c<64;c++) s += (double)WA[c]*(double)bc2[c]; *bEff = s; }
}

// ---------------- prep 2: rate-encode probabilities (f64) ----------------
__global__ void prep_probs(const float* __restrict__ x, double* __restrict__ probs, int B)
{
  int b = blockIdx.x, k = (int)threadIdx.x;
  if (b >= B || k >= 24) return;
  double* pb = probs + (size_t)b*24;
  if (k >= 18){ pb[k] = -1.0; return; }  // padding: never fires
  int fk, g0, gn;
  if (k < 12){ fk = k;          g0 = 0;  gn = 12; }
  else if (k < 15){ fk = 6+(k-12);  g0 = 6;  gn = 6; }
  else           { fk = 12+(k-15); g0 = 12; gn = 6; }
  const float* xb = x + (size_t)b*18;
  double mn = (double)xb[g0], mx = mn;
  for (int f = 1; f < gn; f++){ double v = (double)xb[g0+f]; mn = fmin(mn, v); mx = fmax(mx, v); }
  double rng = mx - mn; if (rng == 0.0) rng = 1.0;
  double norm = ((double)xb[fk] - mn) / rng;
  double p = (100.0 * norm) * 0.001;
  p = fmin(fmax(p, 0.0), 1.0);
  pb[k] = p;
}

// ---------------- prep 3: pack all input spike bits into one u32 per (t,b) ----------------
__global__ void prep_enc(const float* __restrict__ u1, const float* __restrict__ u2,
                         const float* __restrict__ u3, const double* __restrict__ probs,
                         unsigned* __restrict__ enc, int B)
{
  int b = blockIdx.x * blockDim.x + (int)threadIdx.x;
  int t = blockIdx.y;
  if (b >= B) return;
  const double* pb = probs + (size_t)b*24;
  size_t r = (size_t)t * B + b;
  const float* a1 = u1 + r*12;
  const float* a2 = u2 + r*6;
  const float* a3 = u3 + r*6;
  unsigned e = 0;
  #pragma unroll
  for (int k = 0; k < 12; k++) if ((double)a1[k] < pb[k])    e |= (1u << k);
  #pragma unroll
  for (int h = 0; h < 3; h++)  if ((double)a2[h] < pb[12+h]) e |= (1u << (12+h));
  #pragma unroll
  for (int h = 0; h < 3; h++)  if ((double)a3[h] < pb[15+h]) e |= (1u << (15+h));
  enc[r] = e;
}

// ---------------- main: one wave per batch row, 200-step serial LIF chain ----------------
// Lane l owns neurons j = 4l..4l+3 of layers 1&2. Spike masks wave-uniform in SGPRs
// (ballot / readfirstlane) -> mask loops on SALU, gathers are saddr-form f64 loads.
__global__ __launch_bounds__(256) void snn_main(
    const unsigned* __restrict__ enc,
    const float* __restrict__ b1, const float* __restrict__ b2, const float* __restrict__ b3,
    const float* __restrict__ Wc1, const float* __restrict__ bc1,
    const double* __restrict__ Wt1, const double* __restrict__ Wt2, const double* __restrict__ Wt3,
    const double* __restrict__ wEff, const double* __restrict__ bEff,
    float* __restrict__ out, int B, int T)
{
  const int lane = (int)(threadIdx.x & 63);
  const int b = blockIdx.x * 4 + (int)(threadIdx.x >> 6);
  if (b >= B) return;
  const int l4 = lane << 2;
  const int lcl = (lane < 3) ? lane : 3;   // Wt3 col (col3 = 0 pad)

  const float4 b1f = *(const float4*)(b1 + l4);
  const float4 b2f = *(const float4*)(b2 + l4);
  const double b1d0=b1f.x, b1d1=b1f.y, b1d2=b1f.z, b1d3=b1f.w;
  const double b2d0=b2f.x, b2d1=b2f.y, b2d2=b2f.z, b2d3=b2f.w;
  const double b3d = (lane < 3) ? (double)b3[lane] : 0.0;
  double wc1a=0.0, wc1b=0.0, wc1c=0.0, bc1d=0.0, wEd=0.0;
  if (lane < 32){
    wc1a = (double)Wc1[lane*3+0];
    wc1b = (double)Wc1[lane*3+1];
    wc1c = (double)Wc1[lane*3+2];
    bc1d = (double)bc1[lane];
    wEd  = wEff[lane];
  }

  double m10=0,m11=0,m12=0,m13=0;     // layer1 mem
  double m20=0,m21=0,m22=0,m23=0;     // layer2 mem
  double m3v=0;                       // layer3 mem (lane<3 -> j=lane)
  double m40=0,m41=0,m42=0;           // layer4 mem (o=lane<32, h=0..2)
  double r10=0,r11=0,r12=0,r13=0;     // pending resets (0.0/1.0), = prev spike
  double r20=0,r21=0,r22=0,r23=0;
  double r3v=0;
  double r40=0,r41=0,r42=0;

  const unsigned* ep = enc + b;
  unsigned e = __builtin_amdgcn_readfirstlane(*ep);

  for (int t = 0; t < T; t++){
    unsigned e_nx = (t+1 < T) ? ep[(size_t)(t+1) * B] : 0u;   // prefetch next step
    const unsigned sm  = e & 0xFFFu;
    const unsigned td  = (e >> 12) & 7u;
    const unsigned td2 = (e >> 15) & 7u;

    // ---- layer 1: cur1 = b1 + sum over active input bits (unroll 2) ----
    double c0=b1d0, c1=b1d1, c2=b1d2, c3=b1d3;
    {
      unsigned w = sm;
      while (w){
        int k0 = __builtin_ctz(w); w &= w-1;
        int k1 = k0; int n = 1;
        if (w){ k1 = __builtin_ctz(w); w &= w-1; n = 2; }
        const double* rp0 = Wt1 + ((size_t)k0 << 8);
        const double* rp1 = Wt1 + ((size_t)k1 << 8);
        double2 a0 = *(const double2*)(rp0 + l4);
        double2 a1 = *(const double2*)(rp0 + l4 + 2);
        double2 a2 = *(const double2*)(rp1 + l4);
        double2 a3 = *(const double2*)(rp1 + l4 + 2);
        c0 += a0.x; c1 += a0.y; c2 += a1.x; c3 += a1.y;
        if (n > 1){ c0 += a2.x; c1 += a2.y; c2 += a3.x; c3 += a3.y; }
      }
    }
    m10 = 0.9*m10 + c0; m10 -= r10;
    m11 = 0.9*m11 + c1; m11 -= r11;
    m12 = 0.9*m12 + c2; m12 -= r12;
    m13 = 0.9*m13 + c3; m13 -= r13;
    bool sp;
    sp = m10 > 1.0; const u64 s1w0 = __ballot(sp); r10 = sp ? 1.0 : 0.0;
    sp = m11 > 1.0; const u64 s1w1 = __ballot(sp); r11 = sp ? 1.0 : 0.0;
    sp = m12 > 1.0; const u64 s1w2 = __ballot(sp); r12 = sp ? 1.0 : 0.0;
    sp = m13 > 1.0; const u64 s1w3 = __ballot(sp); r13 = sp ? 1.0 : 0.0;

    // ---- layer 2: sparse gather over active spk1, f64 rows, saddr loads (unroll 4) ----
    c0=b2d0; c1=b2d1; c2=b2d2; c3=b2d3;
#define L2LOOP(WREG, CW) { u64 w = (WREG); \
      while (w){ \
        int i0 = ((int)__builtin_ctzll(w)<<2)+(CW); w &= w-1; \
        int i1=i0,i2=i0,i3=i0; int n=1; \
        if (w){ i1=((int)__builtin_ctzll(w)<<2)+(CW); w&=w-1; n=2; \
          if (w){ i2=((int)__builtin_ctzll(w)<<2)+(CW); w&=w-1; n=3; \
            if (w){ i3=((int)__builtin_ctzll(w)<<2)+(CW); w&=w-1; n=4; } } } \
        const double* rp0 = Wt2 + ((size_t)i0 << 8); \
        const double* rp1 = Wt2 + ((size_t)i1 << 8); \
        const double* rp2 = Wt2 + ((size_t)i2 << 8); \
        const double* rp3 = Wt2 + ((size_t)i3 << 8); \
        double2 aa0 = *(const double2*)(rp0 + l4), ab0 = *(const double2*)(rp0 + l4 + 2); \
        double2 aa1 = *(const double2*)(rp1 + l4), ab1 = *(const double2*)(rp1 + l4 + 2); \
        double2 aa2 = *(const double2*)(rp2 + l4), ab2 = *(const double2*)(rp2 + l4 + 2); \
        double2 aa3 = *(const double2*)(rp3 + l4), ab3 = *(const double2*)(rp3 + l4 + 2); \
        c0 += aa0.x; c1 += aa0.y; c2 += ab0.x; c3 += ab0.y; \
        if (n>1){ c0 += aa1.x; c1 += aa1.y; c2 += ab1.x; c3 += ab1.y; } \
        if (n>2){ c0 += aa2.x; c1 += aa2.y; c2 += ab2.x; c3 += ab2.y; } \
        if (n>3){ c0 += aa3.x; c1 += aa3.y; c2 += ab3.x; c3 += ab3.y; } \
      } }
    L2LOOP(s1w0, 0)
    L2LOOP(s1w1, 1)
    L2LOOP(s1w2, 2)
    L2LOOP(s1w3, 3)

    m20 = 0.9*m20 + c0; m20 -= r20;
    m21 = 0.9*m21 + c1; m21 -= r21;
    m22 = 0.9*m22 + c2; m22 -= r22;
    m23 = 0.9*m23 + c3; m23 -= r23;
    sp = m20 > 1.0; const u64 s2w0 = __ballot(sp); r20 = sp ? 1.0 : 0.0;
    sp = m21 > 1.0; const u64 s2w1 = __ballot(sp); r21 = sp ? 1.0 : 0.0;
    sp = m22 > 1.0; const u64 s2w2 = __ballot(sp); r22 = sp ? 1.0 : 0.0;
    sp = m23 > 1.0; const u64 s2w3 = __ballot(sp); r23 = sp ? 1.0 : 0.0;

    // ---- layer 3 (only j=0..2 matter): sparse gather over active spk2 (unroll 4) ----
    double cl3 = b3d;
#define L3LOOP(WREG, CW) { u64 w = (WREG); \
      while (w){ \
        int i0 = ((int)__builtin_ctzll(w)<<2)+(CW); w &= w-1; \
        int i1=i0,i2=i0,i3=i0; int n=1; \
        if (w){ i1=((int)__builtin_ctzll(w)<<2)+(CW); w&=w-1; n=2; \
          if (w){ i2=((int)__builtin_ctzll(w)<<2)+(CW); w&=w-1; n=3; \
            if (w){ i3=((int)__builtin_ctzll(w)<<2)+(CW); w&=w-1; n=4; } } } \
        const double* q0 = Wt3 + ((size_t)i0 << 2); \
        const double* q1 = Wt3 + ((size_t)i1 << 2); \
        const double* q2 = Wt3 + ((size_t)i2 << 2); \
        const double* q3 = Wt3 + ((size_t)i3 << 2); \
        double v0 = q0[lcl], v1 = q1[lcl], v2 = q2[lcl], v3 = q3[lcl]; \
        cl3 += v0; \
        if (n>1) cl3 += v1; \
        if (n>2) cl3 += v2; \
        if (n>3) cl3 += v3; \
      } }
    L3LOOP(s2w0, 0)
    L3LOOP(s2w1, 1)
    L3LOOP(s2w2, 2)
    L3LOOP(s2w3, 3)

    m3v = 0.9*m3v + cl3; m3v -= r3v;
    sp = m3v > 1.0;
    const unsigned s3 = (unsigned)(__ballot((lane < 3) && sp) & 7ull);
    r3v = sp ? 1.0 : 0.0;

    // ---- layer 4 (conv1 LIF): lane<32 = out-channel o, h = 0..2 ----
    double cur;
    cur = bc1d + ((td  & 1u) ? wc1a : 0.0) + ((s3 & 1u) ? wc1b : 0.0) + ((td2 & 1u) ? wc1c : 0.0);
    m40 = 0.9*m40 + cur; m40 -= r40; r40 = (m40 > 1.0) ? 1.0 : 0.0;
    cur = bc1d + ((td  & 2u) ? wc1a : 0.0) + ((s3 & 2u) ? wc1b : 0.0) + ((td2 & 2u) ? wc1c : 0.0);
    m41 = 0.9*m41 + cur; m41 -= r41; r41 = (m41 > 1.0) ? 1.0 : 0.0;
    cur = bc1d + ((td  & 4u) ? wc1a : 0.0) + ((s3 & 4u) ? wc1b : 0.0) + ((td2 & 4u) ? wc1c : 0.0);
    m42 = 0.9*m42 + cur; m42 -= r42; r42 = (m42 > 1.0) ? 1.0 : 0.0;

    e = __builtin_amdgcn_readfirstlane(e_nx);
  }

  // ---- output: out[b,m] = bEff + sum_o spk4_final[o,m] * wEff[o] ----
  double o0 = r40 * wEd;   // r4x already holds final spike (0/1); wEd=0 for lane>=32
  double o1 = r41 * wEd;
  double o2 = r42 * wEd;
  for (int off = 32; off > 0; off >>= 1){
    o0 += __shfl_xor(o0, off, 64);
    o1 += __shfl_xor(o1, off, 64);
    o2 += __shfl_xor(o2, off, 64);
  }
  if (lane == 0){
    const double be = *bEff;
    out[b*3+0] = (float)(o0 + be);
    out[b*3+1] = (float)(o1 + be);
    out[b*3+2] = (float)(o2 + be);
  }
}

// ---------------- host ----------------
extern "C" void kernel_launch(void* const* d_in, const int* in_sizes, int n_in,
                              void* d_out, int out_size, void* d_ws, size_t ws_size,
                              hipStream_t stream)
{
  const float* x   = (const float*)d_in[0];
  const float* u1  = (const float*)d_in[1];
  const float* u2  = (const float*)d_in[2];
  const float* u3  = (const float*)d_in[3];
  const float* W1  = (const float*)d_in[4];
  const float* b1  = (const float*)d_in[5];
  const float* W2  = (const float*)d_in[6];
  const float* b2  = (const float*)d_in[7];
  const float* W3  = (const float*)d_in[8];
  const float* b3  = (const float*)d_in[9];
  const float* Wc1 = (const float*)d_in[10];
  const float* bc1 = (const float*)d_in[11];
  const float* Wc2 = (const float*)d_in[12];
  const float* bc2 = (const float*)d_in[13];
  const float* WA  = (const float*)d_in[14];
  float* out = (float*)d_out;

  const int B = in_sizes[0] / 18;
  const int T = in_sizes[1] / (B * 12);

  char* ws = (char*)d_ws;
  double* Wt2   = (double*)(ws + 0);                         // 256*256*8 = 524288
  double* Wt1   = (double*)(ws + 524288);                    // 12*256*8  = 24576
  double* Wt3   = (double*)(ws + 548864);                    // 256*4*8   = 8192
  double* wEff  = (double*)(ws + 557056);                    // 32*8      = 256
  double* bEff  = (double*)(ws + 557312);                    // 8
  double* probs = (double*)(ws + 557320);                    // B*24*8
  unsigned* enc = (unsigned*)(ws + 557320 + (size_t)B*24*8); // T*B*4

  hipLaunchKernelGGL(prep_weights, dim3(256), dim3(256), 0, stream,
                     W1, W2, W3, Wc2, bc2, WA, Wt1, Wt2, Wt3, wEff, bEff);
  hipLaunchKernelGGL(prep_probs, dim3(B), dim3(64), 0, stream, x, probs, B);
  hipLaunchKernelGGL(prep_enc, dim3((B+255)/256, T), dim3(256), 0, stream,
                     u1, u2, u3, probs, enc, B);
  hipLaunchKernelGGL(snn_main, dim3((B+3)/4), dim3(256), 0, stream,
                     enc, b1, b2, b3, Wc1, bc1, Wt1, Wt2, Wt3, wEff, bEff, out, B, T);
}